// Round 8
// baseline (295.923 us; speedup 1.0000x reference)
//
#include <hip/hip_runtime.h>
#include <stdint.h>

#define DD 128
#define NJ 25000
#define NI 12500
#define OVCAP 65536  // overflow-list capacity per layer (pairs)

__device__ __forceinline__ uint32_t rotl32(uint32_t v, int n) {
  return (v << n) | (v >> (32 - n));
}

// JAX threefry2x32, key=(0,1). Core KAT-verified vs Random123.
__device__ __forceinline__ void threefry_0_1(uint32_t& x0, uint32_t& x1) {
  const uint32_t ks0 = 0u, ks1 = 1u, ks2 = 0x1BD11BDBu;
  x0 += ks0; x1 += ks1;
#define TF_R4(a,b,c,d)                                  \
  x0 += x1; x1 = rotl32(x1,(a)); x1 ^= x0;              \
  x0 += x1; x1 = rotl32(x1,(b)); x1 ^= x0;              \
  x0 += x1; x1 = rotl32(x1,(c)); x1 ^= x0;              \
  x0 += x1; x1 = rotl32(x1,(d)); x1 ^= x0;
  TF_R4(13,15,26,6)   x0 += ks1; x1 += ks2 + 1u;
  TF_R4(17,29,16,24)  x0 += ks2; x1 += ks0 + 2u;
  TF_R4(13,15,26,6)   x0 += ks0; x1 += ks1 + 3u;
  TF_R4(17,29,16,24)  x0 += ks1; x1 += ks2 + 4u;
  TF_R4(13,15,26,6)   x0 += ks2; x1 += ks0 + 5u;
#undef TF_R4
}

// MASK IDENTIFIED (R16 sweep, unique match v5): partitionable threefry,
// ctr = (0, f), 32-bit draw = o0 ^ o1; keep <=> bit31(o0 ^ o1) == 0.
__device__ __forceinline__ bool dropout_keep(uint32_t f) {
  uint32_t x0 = 0u, x1 = f;
  threefry_0_1(x0, x1);
  return ((x0 ^ x1) >> 31) == 0u;
}

__device__ __forceinline__ float4 ld4(const float* p) {
  return *(const float4*)p;
}

// Per-block inline int64-as-int32-pairs detect (odd words zero; L2-hit).
__device__ __forceinline__ int detect_flag_block(const int* __restrict__ w,
                                                 int* sf) {
  if (threadIdx.x == 0) {
    int is64 = 1;
    for (int e = 0; e < 16; ++e)
      if (w[2 * e + 1] != 0) is64 = 0;
    *sf = is64;
  }
  __syncthreads();
  return *sf;
}

// One-pass padded-bucket CSR build fused with weight prep.
//   blocks 0..255 : weight prep for BOTH layers
//   blocks 256..  : edge pass — pos=atomicAdd(cnt[d]); bucket or overflow
// cnt arrays pre-zeroed by memsetAsync. Overflow (deg>CAP) edges go to a
// compact (d,s) list; gather handles them exactly (rare: Poisson(~24) tail).
// WTp[(k>>2)*512 + c*4 + (k&3)] = Wcat[c][k]; Wcat = [W_l | W_r] along k.
__global__ void setup_bucket(const float* __restrict__ Wl1,
                             const float* __restrict__ Wr1,
                             float* __restrict__ WT1,
                             const float* __restrict__ Wl2,
                             const float* __restrict__ Wr2,
                             float* __restrict__ WT2,
                             const int* __restrict__ adj1,
                             const int* __restrict__ adj2,
                             int* __restrict__ cnt1, int* __restrict__ cnt2,
                             int* __restrict__ ovCnt,
                             int* __restrict__ ovList1,
                             int* __restrict__ ovList2,
                             int* __restrict__ bucket1,
                             int* __restrict__ bucket2,
                             int nE1, int nE2, int CAP) {
  const int b = blockIdx.x;
  if (b < 256) {
    int t = b * 256 + threadIdx.x;  // exactly covers 2*DD*256 = 65536
    int which = t >= DD * 256;
    int idx = which ? t - DD * 256 : t;
    const float* Wl = which ? Wl2 : Wl1;
    const float* Wr = which ? Wr2 : Wr1;
    float* WTp = which ? WT2 : WT1;
    int c = idx >> 8;
    int k = idx & 255;
    float v = (k < DD) ? Wl[c * DD + k] : Wr[c * DD + (k - DD)];
    WTp[(k >> 2) * (DD * 4) + c * 4 + (k & 3)] = v;
    return;
  }
  __shared__ int sf;
  const int f = detect_flag_block(adj1, &sf);
  int t = (b - 256) * 256 + threadIdx.x;
  if (t < nE1) {
    int s, d;
    if (f) {
      int2 ps = *(const int2*)(adj1 + 2 * t);
      int2 pd = *(const int2*)(adj1 + 2 * nE1 + 2 * t);
      s = ps.x;
      d = pd.x;
    } else {
      s = adj1[t];
      d = adj1[nE1 + t];
    }
    if (d < NJ) {
      int pos = atomicAdd(&cnt1[d], 1);
      if (pos < CAP) {
        bucket1[(size_t)d * CAP + pos] = s;
      } else {
        int op = atomicAdd(&ovCnt[0], 1);
        if (op < OVCAP) { ovList1[2 * op] = d; ovList1[2 * op + 1] = s; }
      }
    }
  } else if (t < nE1 + nE2) {
    int e = t - nE1;
    int s, d;
    if (f) {
      int2 ps = *(const int2*)(adj2 + 2 * e);
      int2 pd = *(const int2*)(adj2 + 2 * nE2 + 2 * e);
      s = ps.x;
      d = pd.x;
    } else {
      s = adj2[e];
      d = adj2[nE2 + e];
    }
    if (d < NI) {
      int pos = atomicAdd(&cnt2[d], 1);
      if (pos < CAP) {
        bucket2[(size_t)d * CAP + pos] = s;
      } else {
        int op = atomicAdd(&ovCnt[1], 1);
        if (op < OVCAP) { ovList2[2 * op] = d; ovList2[2 * op + 1] = s; }
      }
    }
  }
}

// Fused gather + dense, 512 threads/block (8 waves — 2x gather MLP vs the
// 256-thread variant at IDENTICAL grid + W-traffic; this targets the
// latency-bound gather: ~24 resident waves/CU instead of ~12).
// ROWS=32 (layer1), 16 (layer2); grid = 782 blocks either way.
// Gather: 16 teams x 32 lanes, ROWS/16 rows per team, lane owns 16 B.
// Dense: 16 row-groups; thread owns ROWS/16 rows x 4 cols. Per-wave As
// broadcasts hit 2 addresses (2-way LDS aliasing is free, m136).
// LAYER==1: relu + dropout epilogue.
template <int ROWS, int LAYER>
__global__ __launch_bounds__(512) void dense_kernel(
    const float* __restrict__ xsrc, const int* __restrict__ bucket,
    const int* __restrict__ cnt, const int* __restrict__ ovCnt,
    const int* __restrict__ ovList, const float* __restrict__ xin,
    const float* __restrict__ WTp, const float* __restrict__ bias,
    float* __restrict__ out, int M, int CAP) {
  __shared__ float As[ROWS * 256];
  const int tid = threadIdx.x;
  const int rowBase = blockIdx.x * ROWS;
  constexpr int RPT = ROWS / 16;  // rows per team == rows per thread

  // ---- gather phase ----
  {
    const int team = tid >> 5;      // 0..15
    const int l4 = (tid & 31) * 4;  // float4 slot within row
#pragma unroll
    for (int rr = 0; rr < RPT; ++rr) {
      const int r = team * RPT + rr;
      int rg = rowBase + r;
      if (rg >= M) rg = M - 1;  // clamped read; stores guarded below
      const int deg = cnt[rg];
      const int nb = (deg < CAP) ? deg : CAP;
      const int* bk = bucket + (size_t)rg * CAP;
      float4 a0 = {0.f, 0.f, 0.f, 0.f}, a1 = a0, a2 = a0, a3 = a0;
      int e = 0;
      for (; e + 7 < nb; e += 8) {
        int s0 = bk[e], s1 = bk[e + 1], s2 = bk[e + 2], s3 = bk[e + 3];
        int s4 = bk[e + 4], s5 = bk[e + 5], s6 = bk[e + 6], s7 = bk[e + 7];
        float4 v0 = ld4(xsrc + (size_t)s0 * DD + l4);
        float4 v1 = ld4(xsrc + (size_t)s1 * DD + l4);
        float4 v2 = ld4(xsrc + (size_t)s2 * DD + l4);
        float4 v3 = ld4(xsrc + (size_t)s3 * DD + l4);
        float4 v4 = ld4(xsrc + (size_t)s4 * DD + l4);
        float4 v5 = ld4(xsrc + (size_t)s5 * DD + l4);
        float4 v6 = ld4(xsrc + (size_t)s6 * DD + l4);
        float4 v7 = ld4(xsrc + (size_t)s7 * DD + l4);
        a0.x += v0.x; a0.y += v0.y; a0.z += v0.z; a0.w += v0.w;
        a1.x += v1.x; a1.y += v1.y; a1.z += v1.z; a1.w += v1.w;
        a2.x += v2.x; a2.y += v2.y; a2.z += v2.z; a2.w += v2.w;
        a3.x += v3.x; a3.y += v3.y; a3.z += v3.z; a3.w += v3.w;
        a0.x += v4.x; a0.y += v4.y; a0.z += v4.z; a0.w += v4.w;
        a1.x += v5.x; a1.y += v5.y; a1.z += v5.z; a1.w += v5.w;
        a2.x += v6.x; a2.y += v6.y; a2.z += v6.z; a2.w += v6.w;
        a3.x += v7.x; a3.y += v7.y; a3.z += v7.z; a3.w += v7.w;
      }
      for (; e + 3 < nb; e += 4) {
        int s0 = bk[e], s1 = bk[e + 1], s2 = bk[e + 2], s3 = bk[e + 3];
        float4 v0 = ld4(xsrc + (size_t)s0 * DD + l4);
        float4 v1 = ld4(xsrc + (size_t)s1 * DD + l4);
        float4 v2 = ld4(xsrc + (size_t)s2 * DD + l4);
        float4 v3 = ld4(xsrc + (size_t)s3 * DD + l4);
        a0.x += v0.x; a0.y += v0.y; a0.z += v0.z; a0.w += v0.w;
        a1.x += v1.x; a1.y += v1.y; a1.z += v1.z; a1.w += v1.w;
        a2.x += v2.x; a2.y += v2.y; a2.z += v2.z; a2.w += v2.w;
        a3.x += v3.x; a3.y += v3.y; a3.z += v3.z; a3.w += v3.w;
      }
      for (; e < nb; ++e) {
        float4 v = ld4(xsrc + (size_t)bk[e] * DD + l4);
        a0.x += v.x; a0.y += v.y; a0.z += v.z; a0.w += v.w;
      }
      if (deg > CAP) {  // rare: scan compact overflow list for this row
        int ovc = *ovCnt;
        if (ovc > OVCAP) ovc = OVCAP;
        for (int o = 0; o < ovc; ++o) {
          if (ovList[2 * o] == rg) {
            float4 v = ld4(xsrc + (size_t)ovList[2 * o + 1] * DD + l4);
            a0.x += v.x; a0.y += v.y; a0.z += v.z; a0.w += v.w;
          }
        }
      }
      a0.x += a1.x + a2.x + a3.x;
      a0.y += a1.y + a2.y + a3.y;
      a0.z += a1.z + a2.z + a3.z;
      a0.w += a1.w + a2.w + a3.w;
      float rdeg = 1.0f / fmaxf((float)deg, 1.0f);
      a0.x *= rdeg; a0.y *= rdeg; a0.z *= rdeg; a0.w *= rdeg;
      *(float4*)(As + r * 256 + l4) = a0;
      *(float4*)(As + r * 256 + DD + l4) = ld4(xin + (size_t)rg * DD + l4);
    }
  }
  __syncthreads();

  // ---- dense phase: RPT rows x 4 cols per thread ----
  const int u = tid & 31;   // cols u, u+32, u+64, u+96
  const int g = tid >> 5;   // row group 0..15 (half-wave-uniform)
  const int r0 = g * RPT;
  float acc[RPT][4];
#pragma unroll
  for (int r = 0; r < RPT; ++r)
    acc[r][0] = acc[r][1] = acc[r][2] = acc[r][3] = 0.f;

#pragma unroll 8
  for (int k0 = 0; k0 < 256; k0 += 4) {
    const float* wbase = WTp + (k0 >> 2) * (DD * 4);
    float4 w0 = ld4(wbase + u * 4);
    float4 w1 = ld4(wbase + (u + 32) * 4);
    float4 w2 = ld4(wbase + (u + 64) * 4);
    float4 w3 = ld4(wbase + (u + 96) * 4);
#pragma unroll
    for (int r = 0; r < RPT; ++r) {
      float4 a = *(const float4*)(As + (r0 + r) * 256 + k0);
      acc[r][0] += a.x * w0.x + a.y * w0.y + a.z * w0.z + a.w * w0.w;
      acc[r][1] += a.x * w1.x + a.y * w1.y + a.z * w1.z + a.w * w1.w;
      acc[r][2] += a.x * w2.x + a.y * w2.y + a.z * w2.z + a.w * w2.w;
      acc[r][3] += a.x * w3.x + a.y * w3.y + a.z * w3.z + a.w * w3.w;
    }
  }

  float bb[4] = {bias[u], bias[u + 32], bias[u + 64], bias[u + 96]};
#pragma unroll
  for (int r = 0; r < RPT; ++r) {
    int rg = rowBase + r0 + r;
    if (rg >= M) continue;
#pragma unroll
    for (int i = 0; i < 4; ++i) {
      int cc = u + 32 * i;
      float v = acc[r][i] + bb[i];
      if (LAYER == 1) {
        v = fmaxf(v, 0.0f);
        v = dropout_keep((uint32_t)rg * DD + (uint32_t)cc) ? v * 2.0f : 0.0f;
      }
      out[(size_t)rg * DD + cc] = v;
    }
  }
}

extern "C" void kernel_launch(void* const* d_in, const int* in_sizes, int n_in,
                              void* d_out, int out_size, void* d_ws, size_t ws_size,
                              hipStream_t stream) {
  const float* feat = (const float*)d_in[0];   // fp32 (R4 NaN proof)
  const int* t_adj = (const int*)d_in[1];
  const int* n_adj = (const int*)d_in[2];
  const float* W1l = (const float*)d_in[5];
  const float* b1 = (const float*)d_in[6];
  const float* W1r = (const float*)d_in[7];
  const float* W2l = (const float*)d_in[8];
  const float* b2 = (const float*)d_in[9];
  const float* W2r = (const float*)d_in[10];

  const int E1 = in_sizes[1] / 2;
  const int E2 = in_sizes[2] / 2;

  // Workspace layout (ints unless noted). CAP sized from ws_size.
  float* ws = (float*)d_ws;
  float* x1 = ws;                          // 3,200,000 f
  float* WT1 = x1 + 3200000;               //    32,768 f
  float* WT2 = WT1 + 32768;                //    32,768 f
  int* cnt1 = (int*)(WT2 + 32768);         //    NJ
  int* cnt2 = cnt1 + NJ;                   //    NI
  int* ovCnt = cnt2 + NI;                  //    8 (2 used)
  int* ovList1 = ovCnt + 8;                //    2*OVCAP
  int* ovList2 = ovList1 + 2 * OVCAP;      //    2*OVCAP
  int* bucket1 = ovList2 + 2 * OVCAP;      //    NJ*CAP

  const long fixedInts = 3200000L + 32768 + 32768 + NJ + NI + 8 + 4L * OVCAP;
  long capInts = (long)(ws_size / 4) - fixedInts;
  int CAP = (int)(capInts / (NJ + NI));
  if (CAP > 64) CAP = 64;
  if (CAP < 16) CAP = 16;  // ws proven >= 19.6 MB by earlier rounds => >= 41

  int* bucket2 = bucket1 + (size_t)NJ * CAP;  // NI*CAP

  // Zero cnt1, cnt2, ovCnt (contiguous): (NJ+NI+8) ints.
  hipMemsetAsync(cnt1, 0, (size_t)(NJ + NI + 8) * sizeof(int), stream);

  const int nTot = E1 + E2;
  setup_bucket<<<256 + (nTot + 255) / 256, 256, 0, stream>>>(
      W1l, W1r, WT1, W2l, W2r, WT2, t_adj, n_adj, cnt1, cnt2, ovCnt, ovList1,
      ovList2, bucket1, bucket2, E1, E2, CAP);

  dense_kernel<32, 1><<<(NJ + 31) / 32, 512, 0, stream>>>(
      feat, bucket1, cnt1, ovCnt + 0, ovList1, feat, WT1, b1, x1, NJ, CAP);
  dense_kernel<16, 2><<<(NI + 15) / 16, 512, 0, stream>>>(
      x1, bucket2, cnt2, ovCnt + 1, ovList2, x1, WT2, b2, (float*)d_out, NI,
      CAP);
}

// Round 9
// 230.683 us; speedup vs baseline: 1.2828x; 1.2828x over previous
//
#include <hip/hip_runtime.h>
#include <stdint.h>

#define DD 128
#define NJ 25000
#define NI 12500
#define OVCAP 65536  // overflow-list capacity per layer (pairs)

__device__ __forceinline__ uint32_t rotl32(uint32_t v, int n) {
  return (v << n) | (v >> (32 - n));
}

// JAX threefry2x32, key=(0,1). Core KAT-verified vs Random123.
__device__ __forceinline__ void threefry_0_1(uint32_t& x0, uint32_t& x1) {
  const uint32_t ks0 = 0u, ks1 = 1u, ks2 = 0x1BD11BDBu;
  x0 += ks0; x1 += ks1;
#define TF_R4(a,b,c,d)                                  \
  x0 += x1; x1 = rotl32(x1,(a)); x1 ^= x0;              \
  x0 += x1; x1 = rotl32(x1,(b)); x1 ^= x0;              \
  x0 += x1; x1 = rotl32(x1,(c)); x1 ^= x0;              \
  x0 += x1; x1 = rotl32(x1,(d)); x1 ^= x0;
  TF_R4(13,15,26,6)   x0 += ks1; x1 += ks2 + 1u;
  TF_R4(17,29,16,24)  x0 += ks2; x1 += ks0 + 2u;
  TF_R4(13,15,26,6)   x0 += ks0; x1 += ks1 + 3u;
  TF_R4(17,29,16,24)  x0 += ks1; x1 += ks2 + 4u;
  TF_R4(13,15,26,6)   x0 += ks2; x1 += ks0 + 5u;
#undef TF_R4
}

// MASK IDENTIFIED (R16 sweep, unique match v5): partitionable threefry,
// ctr = (0, f), 32-bit draw = o0 ^ o1; keep <=> bit31(o0 ^ o1) == 0.
__device__ __forceinline__ bool dropout_keep(uint32_t f) {
  uint32_t x0 = 0u, x1 = f;
  threefry_0_1(x0, x1);
  return ((x0 ^ x1) >> 31) == 0u;
}

__device__ __forceinline__ float4 ld4(const float* p) {
  return *(const float4*)p;
}

// Per-block inline int64-as-int32-pairs detect (odd words zero; L2-hit).
__device__ __forceinline__ int detect_flag_block(const int* __restrict__ w,
                                                 int* sf) {
  if (threadIdx.x == 0) {
    int is64 = 1;
    for (int e = 0; e < 16; ++e)
      if (w[2 * e + 1] != 0) is64 = 0;
    *sf = is64;
  }
  __syncthreads();
  return *sf;
}

// One-pass padded-bucket CSR build fused with weight prep.
//   blocks 0..255 : weight prep for BOTH layers
//   blocks 256..  : edge pass — pos=atomicAdd(cnt[d]); bucket or overflow
// cnt arrays pre-zeroed by memsetAsync. Overflow (deg>CAP) edges go to a
// compact (d,s) list; gather handles them exactly (rare: Poisson(~24) tail).
// WTp[(k>>2)*512 + c*4 + (k&3)] = Wcat[c][k]; Wcat = [W_l | W_r] along k.
__global__ void setup_bucket(const float* __restrict__ Wl1,
                             const float* __restrict__ Wr1,
                             float* __restrict__ WT1,
                             const float* __restrict__ Wl2,
                             const float* __restrict__ Wr2,
                             float* __restrict__ WT2,
                             const int* __restrict__ adj1,
                             const int* __restrict__ adj2,
                             int* __restrict__ cnt1, int* __restrict__ cnt2,
                             int* __restrict__ ovCnt,
                             int* __restrict__ ovList1,
                             int* __restrict__ ovList2,
                             int* __restrict__ bucket1,
                             int* __restrict__ bucket2,
                             int nE1, int nE2, int CAP) {
  const int b = blockIdx.x;
  if (b < 256) {
    int t = b * 256 + threadIdx.x;  // exactly covers 2*DD*256 = 65536
    int which = t >= DD * 256;
    int idx = which ? t - DD * 256 : t;
    const float* Wl = which ? Wl2 : Wl1;
    const float* Wr = which ? Wr2 : Wr1;
    float* WTp = which ? WT2 : WT1;
    int c = idx >> 8;
    int k = idx & 255;
    float v = (k < DD) ? Wl[c * DD + k] : Wr[c * DD + (k - DD)];
    WTp[(k >> 2) * (DD * 4) + c * 4 + (k & 3)] = v;
    return;
  }
  __shared__ int sf;
  const int f = detect_flag_block(adj1, &sf);
  int t = (b - 256) * 256 + threadIdx.x;
  if (t < nE1) {
    int s, d;
    if (f) {
      int2 ps = *(const int2*)(adj1 + 2 * t);
      int2 pd = *(const int2*)(adj1 + 2 * nE1 + 2 * t);
      s = ps.x;
      d = pd.x;
    } else {
      s = adj1[t];
      d = adj1[nE1 + t];
    }
    if (d < NJ) {
      int pos = atomicAdd(&cnt1[d], 1);
      if (pos < CAP) {
        bucket1[(size_t)d * CAP + pos] = s;
      } else {
        int op = atomicAdd(&ovCnt[0], 1);
        if (op < OVCAP) { ovList1[2 * op] = d; ovList1[2 * op + 1] = s; }
      }
    }
  } else if (t < nE1 + nE2) {
    int e = t - nE1;
    int s, d;
    if (f) {
      int2 ps = *(const int2*)(adj2 + 2 * e);
      int2 pd = *(const int2*)(adj2 + 2 * nE2 + 2 * e);
      s = ps.x;
      d = pd.x;
    } else {
      s = adj2[e];
      d = adj2[nE2 + e];
    }
    if (d < NI) {
      int pos = atomicAdd(&cnt2[d], 1);
      if (pos < CAP) {
        bucket2[(size_t)d * CAP + pos] = s;
      } else {
        int op = atomicAdd(&ovCnt[1], 1);
        if (op < OVCAP) { ovList2[2 * op] = d; ovList2[2 * op + 1] = s; }
      }
    }
  }
}

// Fused gather + dense, 256 threads (R7 config: 48 VGPR, best measured).
// ROWS=32 (layer1), 16 (layer2).
// Gather: 8 teams x 32 lanes, ROWS/8 rows per team, lane owns 16 B.
//   NEW (R9): indices fetched as int4 pairs and SOFTWARE-PIPELINED one
//   batch ahead — batch k+1's index load overlaps batch k's feature loads,
//   breaking the idx->feat serial latency chain (2 hops -> ~1).
// Dense: thread owns ROWS/8 rows x 4 cols; As reads are wave-uniform.
// LAYER==1: relu + dropout epilogue.
template <int ROWS, int LAYER>
__global__ __launch_bounds__(256) void dense_kernel(
    const float* __restrict__ xsrc, const int* __restrict__ bucket,
    const int* __restrict__ cnt, const int* __restrict__ ovCnt,
    const int* __restrict__ ovList, const float* __restrict__ xin,
    const float* __restrict__ WTp, const float* __restrict__ bias,
    float* __restrict__ out, int M, int CAP) {
  __shared__ float As[ROWS * 256];
  const int tid = threadIdx.x;
  const int rowBase = blockIdx.x * ROWS;
  constexpr int RPT = ROWS / 8;  // rows per gather-team == rows per thread

  // ---- gather phase ----
  {
    const int team = tid >> 5;      // 0..7
    const int l4 = (tid & 31) * 4;  // float4 slot within row
#pragma unroll
    for (int rr = 0; rr < RPT; ++rr) {
      const int r = team * RPT + rr;
      int rg = rowBase + r;
      if (rg >= M) rg = M - 1;  // clamped read; stores guarded below
      const int deg = cnt[rg];
      const int nb = (deg < CAP) ? deg : CAP;
      const int* bk = bucket + (size_t)rg * CAP;  // 16B-aligned (CAP%8==0)
      const int4* bi4 = (const int4*)bk;
      float4 a0 = {0.f, 0.f, 0.f, 0.f}, a1 = a0, a2 = a0, a3 = a0;
      int4 i0 = {0, 0, 0, 0}, i1 = i0;
      if (nb >= 8) { i0 = bi4[0]; i1 = bi4[1]; }
      int e = 0;
      for (; e + 7 < nb; e += 8) {
        // prefetch next batch's indices (clamped to a safe in-bounds slot;
        // the clamped value is only consumed when the loop exits anyway)
        int p = e + 8;
        if (p > nb - 8) p = 0;
        int4 n0 = bi4[p >> 2];
        int4 n1 = bi4[(p >> 2) + 1];
        float4 v0 = ld4(xsrc + (size_t)i0.x * DD + l4);
        float4 v1 = ld4(xsrc + (size_t)i0.y * DD + l4);
        float4 v2 = ld4(xsrc + (size_t)i0.z * DD + l4);
        float4 v3 = ld4(xsrc + (size_t)i0.w * DD + l4);
        float4 v4 = ld4(xsrc + (size_t)i1.x * DD + l4);
        float4 v5 = ld4(xsrc + (size_t)i1.y * DD + l4);
        float4 v6 = ld4(xsrc + (size_t)i1.z * DD + l4);
        float4 v7 = ld4(xsrc + (size_t)i1.w * DD + l4);
        a0.x += v0.x; a0.y += v0.y; a0.z += v0.z; a0.w += v0.w;
        a1.x += v1.x; a1.y += v1.y; a1.z += v1.z; a1.w += v1.w;
        a2.x += v2.x; a2.y += v2.y; a2.z += v2.z; a2.w += v2.w;
        a3.x += v3.x; a3.y += v3.y; a3.z += v3.z; a3.w += v3.w;
        a0.x += v4.x; a0.y += v4.y; a0.z += v4.z; a0.w += v4.w;
        a1.x += v5.x; a1.y += v5.y; a1.z += v5.z; a1.w += v5.w;
        a2.x += v6.x; a2.y += v6.y; a2.z += v6.z; a2.w += v6.w;
        a3.x += v7.x; a3.y += v7.y; a3.z += v7.z; a3.w += v7.w;
        i0 = n0;
        i1 = n1;
      }
      for (; e < nb; ++e) {
        float4 v = ld4(xsrc + (size_t)bk[e] * DD + l4);
        a0.x += v.x; a0.y += v.y; a0.z += v.z; a0.w += v.w;
      }
      if (deg > CAP) {  // rare: scan compact overflow list for this row
        int ovc = *ovCnt;
        if (ovc > OVCAP) ovc = OVCAP;
        for (int o = 0; o < ovc; ++o) {
          if (ovList[2 * o] == rg) {
            float4 v = ld4(xsrc + (size_t)ovList[2 * o + 1] * DD + l4);
            a0.x += v.x; a0.y += v.y; a0.z += v.z; a0.w += v.w;
          }
        }
      }
      a0.x += a1.x + a2.x + a3.x;
      a0.y += a1.y + a2.y + a3.y;
      a0.z += a1.z + a2.z + a3.z;
      a0.w += a1.w + a2.w + a3.w;
      float rdeg = 1.0f / fmaxf((float)deg, 1.0f);
      a0.x *= rdeg; a0.y *= rdeg; a0.z *= rdeg; a0.w *= rdeg;
      *(float4*)(As + r * 256 + l4) = a0;
      *(float4*)(As + r * 256 + DD + l4) = ld4(xin + (size_t)rg * DD + l4);
    }
  }
  __syncthreads();

  // ---- dense phase: RPT rows x 4 cols per thread ----
  const int u = tid & 31;   // cols u, u+32, u+64, u+96
  const int g = tid >> 5;   // row group 0..7 (wave-uniform)
  const int r0 = g * RPT;
  float acc[RPT][4];
#pragma unroll
  for (int r = 0; r < RPT; ++r)
    acc[r][0] = acc[r][1] = acc[r][2] = acc[r][3] = 0.f;

#pragma unroll 8
  for (int k0 = 0; k0 < 256; k0 += 4) {
    const float* wbase = WTp + (k0 >> 2) * (DD * 4);
    float4 w0 = ld4(wbase + u * 4);
    float4 w1 = ld4(wbase + (u + 32) * 4);
    float4 w2 = ld4(wbase + (u + 64) * 4);
    float4 w3 = ld4(wbase + (u + 96) * 4);
#pragma unroll
    for (int r = 0; r < RPT; ++r) {
      float4 a = *(const float4*)(As + (r0 + r) * 256 + k0);
      acc[r][0] += a.x * w0.x + a.y * w0.y + a.z * w0.z + a.w * w0.w;
      acc[r][1] += a.x * w1.x + a.y * w1.y + a.z * w1.z + a.w * w1.w;
      acc[r][2] += a.x * w2.x + a.y * w2.y + a.z * w2.z + a.w * w2.w;
      acc[r][3] += a.x * w3.x + a.y * w3.y + a.z * w3.z + a.w * w3.w;
    }
  }

  float bb[4] = {bias[u], bias[u + 32], bias[u + 64], bias[u + 96]};
#pragma unroll
  for (int r = 0; r < RPT; ++r) {
    int rg = rowBase + r0 + r;
    if (rg >= M) continue;
#pragma unroll
    for (int i = 0; i < 4; ++i) {
      int cc = u + 32 * i;
      float v = acc[r][i] + bb[i];
      if (LAYER == 1) {
        v = fmaxf(v, 0.0f);
        v = dropout_keep((uint32_t)rg * DD + (uint32_t)cc) ? v * 2.0f : 0.0f;
      }
      out[(size_t)rg * DD + cc] = v;
    }
  }
}

extern "C" void kernel_launch(void* const* d_in, const int* in_sizes, int n_in,
                              void* d_out, int out_size, void* d_ws, size_t ws_size,
                              hipStream_t stream) {
  const float* feat = (const float*)d_in[0];   // fp32 (R4 NaN proof)
  const int* t_adj = (const int*)d_in[1];
  const int* n_adj = (const int*)d_in[2];
  const float* W1l = (const float*)d_in[5];
  const float* b1 = (const float*)d_in[6];
  const float* W1r = (const float*)d_in[7];
  const float* W2l = (const float*)d_in[8];
  const float* b2 = (const float*)d_in[9];
  const float* W2r = (const float*)d_in[10];

  const int E1 = in_sizes[1] / 2;
  const int E2 = in_sizes[2] / 2;

  // Workspace layout (ints unless noted). CAP sized from ws_size.
  float* ws = (float*)d_ws;
  float* x1 = ws;                          // 3,200,000 f
  float* WT1 = x1 + 3200000;               //    32,768 f
  float* WT2 = WT1 + 32768;                //    32,768 f
  int* cnt1 = (int*)(WT2 + 32768);         //    NJ
  int* cnt2 = cnt1 + NJ;                   //    NI
  int* ovCnt = cnt2 + NI;                  //    8 (2 used)
  int* ovList1 = ovCnt + 8;                //    2*OVCAP
  int* ovList2 = ovList1 + 2 * OVCAP;      //    2*OVCAP
  int* bucket1 = ovList2 + 2 * OVCAP;      //    NJ*CAP

  const long fixedInts = 3200000L + 32768 + 32768 + NJ + NI + 8 + 4L * OVCAP;
  long capInts = (long)(ws_size / 4) - fixedInts;
  int CAP = (int)(capInts / (NJ + NI));
  if (CAP > 64) CAP = 64;
  if (CAP < 16) CAP = 16;  // ws proven >= 19.6 MB by earlier rounds => >= 41
  CAP &= ~7;               // multiple of 8: 16B-aligned bucket rows (int4)

  int* bucket2 = bucket1 + (size_t)NJ * CAP;  // NI*CAP

  // Zero cnt1, cnt2, ovCnt (contiguous): (NJ+NI+8) ints.
  hipMemsetAsync(cnt1, 0, (size_t)(NJ + NI + 8) * sizeof(int), stream);

  const int nTot = E1 + E2;
  setup_bucket<<<256 + (nTot + 255) / 256, 256, 0, stream>>>(
      W1l, W1r, WT1, W2l, W2r, WT2, t_adj, n_adj, cnt1, cnt2, ovCnt, ovList1,
      ovList2, bucket1, bucket2, E1, E2, CAP);

  dense_kernel<32, 1><<<(NJ + 31) / 32, 256, 0, stream>>>(
      feat, bucket1, cnt1, ovCnt + 0, ovList1, feat, WT1, b1, x1, NJ, CAP);
  dense_kernel<16, 2><<<(NI + 15) / 16, 256, 0, stream>>>(
      x1, bucket2, cnt2, ovCnt + 1, ovList2, x1, WT2, b2, (float*)d_out, NI,
      CAP);
}